// Round 1
// baseline (6246.176 us; speedup 1.0000x reference)
//
#include <hip/hip_runtime.h>

#define N_NODES 100000
#define D 128
#define N_ADJ 6
#define NNZ 600000
#define N_HOPS 7
#define EDGES_TOTAL (N_ADJ * NNZ)

// ---------------------------------------------------------------------------
// Phase 0: mix = softmax(linear_weight), 7 elements -> d_ws
// ---------------------------------------------------------------------------
__global__ void softmax_mix_kernel(const float* __restrict__ lw,
                                   float* __restrict__ mix) {
    if (threadIdx.x == 0) {
        float m = lw[0];
        for (int i = 1; i < N_HOPS; ++i) m = fmaxf(m, lw[i]);
        float e[N_HOPS];
        float s = 0.f;
        for (int i = 0; i < N_HOPS; ++i) { e[i] = __expf(lw[i] - m); s += e[i]; }
        float inv = 1.f / s;
        for (int i = 0; i < N_HOPS; ++i) mix[i] = e[i] * inv;
    }
}

// ---------------------------------------------------------------------------
// Phase 1: rep = mix[0] * input   (vectorized float4)
// ---------------------------------------------------------------------------
__global__ __launch_bounds__(256) void rep_init_kernel(
    const float4* __restrict__ in4, float4* __restrict__ rep4,
    const float* __restrict__ mix) {
    int i = blockIdx.x * blockDim.x + threadIdx.x;
    if (i >= N_NODES * D / 4) return;
    float m0 = mix[0];
    float4 v = in4[i];
    v.x *= m0; v.y *= m0; v.z *= m0; v.w *= m0;
    rep4[i] = v;
}

// ---------------------------------------------------------------------------
// Phase 2: edge scatter. Half-wave (32 lanes) per edge, float4 per lane.
// rep[row] += mix[a+1] * val * input[col]
// ---------------------------------------------------------------------------
__global__ __launch_bounds__(256) void scatter_kernel(
    const int* __restrict__ rows, const int* __restrict__ cols,
    const float* __restrict__ vals, const float4* __restrict__ in4,
    float* __restrict__ rep, const float* __restrict__ mix) {
    long long gid = (long long)blockIdx.x * blockDim.x + threadIdx.x;
    int e = (int)(gid >> 5);   // edge index
    int l = (int)(gid & 31);   // lane within half-wave
    if (e >= EDGES_TOTAL) return;
    int a = e / NNZ;           // adjacency index (magic-mul)
    int row = rows[e];
    int col = cols[e];
    float v = vals[e] * mix[a + 1];
    float4 x = in4[col * 32 + l];
    float* dst = rep + (long long)row * D + l * 4;
    atomicAdd(dst + 0, v * x.x);
    atomicAdd(dst + 1, v * x.y);
    atomicAdd(dst + 2, v * x.z);
    atomicAdd(dst + 3, v * x.w);
}

// ---------------------------------------------------------------------------
// Phase 3: out = rep @ W + bias.  W (128x128 f32 = 64KB) staged in LDS once
// per block; grid-stride over row groups of 8. 256 thr = 8 rows x 32 tc,
// each thread computes 4 consecutive output columns (float4 accumulate).
// ---------------------------------------------------------------------------
__global__ __launch_bounds__(256) void gemm_kernel(
    const float4* __restrict__ rep4, const float4* __restrict__ w4,
    const float4* __restrict__ bias4, float4* __restrict__ out4) {
    __shared__ float4 Wlds[D * (D / 4)];  // [k][j4] -> 4096 float4 = 64KB

    for (int idx = threadIdx.x; idx < D * (D / 4); idx += 256)
        Wlds[idx] = w4[idx];
    __syncthreads();

    int tc = threadIdx.x & 31;        // output column group (4 cols)
    int rlocal = threadIdx.x >> 5;    // 0..7

    for (int base = blockIdx.x * 8; base < N_NODES; base += gridDim.x * 8) {
        int row = base + rlocal;
        if (row >= N_NODES) continue;
        float4 acc = make_float4(0.f, 0.f, 0.f, 0.f);
        const float4* reprow = rep4 + (long long)row * (D / 4);
        #pragma unroll 4
        for (int k4 = 0; k4 < D / 4; ++k4) {
            float4 a = reprow[k4];
            float4 w0 = Wlds[(k4 * 4 + 0) * 32 + tc];
            float4 w1 = Wlds[(k4 * 4 + 1) * 32 + tc];
            float4 w2 = Wlds[(k4 * 4 + 2) * 32 + tc];
            float4 w3 = Wlds[(k4 * 4 + 3) * 32 + tc];
            acc.x += a.x * w0.x; acc.y += a.x * w0.y; acc.z += a.x * w0.z; acc.w += a.x * w0.w;
            acc.x += a.y * w1.x; acc.y += a.y * w1.y; acc.z += a.y * w1.z; acc.w += a.y * w1.w;
            acc.x += a.z * w2.x; acc.y += a.z * w2.y; acc.z += a.z * w2.z; acc.w += a.z * w2.w;
            acc.x += a.w * w3.x; acc.y += a.w * w3.y; acc.z += a.w * w3.z; acc.w += a.w * w3.w;
        }
        float4 b = bias4[tc];
        acc.x += b.x; acc.y += b.y; acc.z += b.z; acc.w += b.w;
        out4[(long long)row * (D / 4) + tc] = acc;
    }
}

// ---------------------------------------------------------------------------
extern "C" void kernel_launch(void* const* d_in, const int* in_sizes, int n_in,
                              void* d_out, int out_size, void* d_ws, size_t ws_size,
                              hipStream_t stream) {
    const float* input         = (const float*)d_in[0];
    const int*   adj_rows      = (const int*)d_in[1];
    const int*   adj_cols      = (const int*)d_in[2];
    const float* adj_vals      = (const float*)d_in[3];
    const float* weight        = (const float*)d_in[4];
    const float* linear_weight = (const float*)d_in[5];
    const float* bias          = (const float*)d_in[6];

    float* out = (float*)d_out;                    // [N_NODES, D]
    float* rep = out + (size_t)N_NODES * D;        // [N_NODES, D]
    float* mix = (float*)d_ws;                     // [7]

    // Phase 0: softmax of mixing weights
    softmax_mix_kernel<<<1, 64, 0, stream>>>(linear_weight, mix);

    // Phase 1: rep = mix[0] * input
    {
        int total = N_NODES * D / 4;
        int blocks = (total + 255) / 256;
        rep_init_kernel<<<blocks, 256, 0, stream>>>(
            (const float4*)input, (float4*)rep, mix);
    }

    // Phase 2: scatter all 6 adjacencies (flat edge list)
    {
        long long threads = (long long)EDGES_TOTAL * 32;
        int blocks = (int)((threads + 255) / 256);
        scatter_kernel<<<blocks, 256, 0, stream>>>(
            adj_rows, adj_cols, adj_vals, (const float4*)input, rep, mix);
    }

    // Phase 3: out = rep @ W + bias
    {
        gemm_kernel<<<2048, 256, 0, stream>>>(
            (const float4*)rep, (const float4*)weight,
            (const float4*)bias, (float4*)out);
    }
}

// Round 2
// 913.237 us; speedup vs baseline: 6.8396x; 6.8396x over previous
//
#include <hip/hip_runtime.h>

#define N_NODES 100000
#define D 128
#define N_ADJ 6
#define NNZ 600000
#define N_HOPS 7
#define EDGES_TOTAL (N_ADJ * NNZ)

#define SCAN_CHUNK 1024
#define SCAN_BLOCKS ((N_NODES + SCAN_CHUNK - 1) / SCAN_CHUNK)  // 98

// ---------------------------------------------------------------------------
// Phase 0: mix = softmax(linear_weight), 7 elements
// ---------------------------------------------------------------------------
__global__ void softmax_mix_kernel(const float* __restrict__ lw,
                                   float* __restrict__ mix) {
    if (threadIdx.x == 0) {
        float m = lw[0];
        for (int i = 1; i < N_HOPS; ++i) m = fmaxf(m, lw[i]);
        float e[N_HOPS];
        float s = 0.f;
        for (int i = 0; i < N_HOPS; ++i) { e[i] = __expf(lw[i] - m); s += e[i]; }
        float inv = 1.f / s;
        for (int i = 0; i < N_HOPS; ++i) mix[i] = e[i] * inv;
    }
}

// ---------------------------------------------------------------------------
// CSR build step 1: histogram of destination rows (int atomics, low contention)
// ---------------------------------------------------------------------------
__global__ __launch_bounds__(256) void hist_kernel(
    const int* __restrict__ rows, int* __restrict__ counts) {
    int e = blockIdx.x * 256 + threadIdx.x;
    if (e < EDGES_TOTAL) atomicAdd(&counts[rows[e]], 1);
}

// ---------------------------------------------------------------------------
// Scan step 1: per-block (1024 elems) totals
// ---------------------------------------------------------------------------
__global__ __launch_bounds__(256) void scan_partial_kernel(
    const int* __restrict__ counts, int* __restrict__ blockSums) {
    __shared__ int lds[256];
    int base = blockIdx.x * SCAN_CHUNK;
    int t = threadIdx.x;
    int s = 0;
    #pragma unroll
    for (int k = 0; k < 4; ++k) {
        int i = base + t * 4 + k;
        s += (i < N_NODES) ? counts[i] : 0;
    }
    lds[t] = s;
    __syncthreads();
    for (int off = 128; off > 0; off >>= 1) {
        if (t < off) lds[t] += lds[t + off];
        __syncthreads();
    }
    if (t == 0) blockSums[blockIdx.x] = lds[0];
}

// ---------------------------------------------------------------------------
// Scan step 2: exclusive scan of the 98 block sums (single thread, trivial)
// ---------------------------------------------------------------------------
__global__ void scan_blocksums_kernel(int* __restrict__ blockSums) {
    if (threadIdx.x == 0) {
        int run = 0;
        for (int i = 0; i < SCAN_BLOCKS; ++i) {
            int c = blockSums[i];
            blockSums[i] = run;
            run += c;
        }
    }
}

// ---------------------------------------------------------------------------
// Scan step 3: intra-block exclusive scan + block offset -> offsets[], pos[]
// ---------------------------------------------------------------------------
__global__ __launch_bounds__(256) void scan_final_kernel(
    const int* __restrict__ counts, const int* __restrict__ blockSums,
    int* __restrict__ offsets, int* __restrict__ pos) {
    __shared__ int lds[256];
    int base = blockIdx.x * SCAN_CHUNK;
    int t = threadIdx.x;
    int c[4];
    int s = 0;
    #pragma unroll
    for (int k = 0; k < 4; ++k) {
        int i = base + t * 4 + k;
        c[k] = (i < N_NODES) ? counts[i] : 0;
        s += c[k];
    }
    lds[t] = s;
    __syncthreads();
    for (int off = 1; off < 256; off <<= 1) {
        int u = 0;
        if (t >= off) u = lds[t - off];
        __syncthreads();
        if (t >= off) lds[t] += u;
        __syncthreads();
    }
    int texcl = lds[t] - s;  // exclusive prefix of this thread within block
    int run = blockSums[blockIdx.x] + texcl;
    #pragma unroll
    for (int k = 0; k < 4; ++k) {
        int i = base + t * 4 + k;
        if (i < N_NODES) { offsets[i] = run; pos[i] = run; }
        run += c[k];
    }
    if (blockIdx.x == 0 && t == 0) offsets[N_NODES] = EDGES_TOTAL;
}

// ---------------------------------------------------------------------------
// CSR build step 2: scatter edges into row-sorted order, premultiplying the
// softmax mixing weight into the edge value. Packed {col, val} int2 writes.
// ---------------------------------------------------------------------------
__global__ __launch_bounds__(256) void build_csr_kernel(
    const int* __restrict__ rows, const int* __restrict__ cols,
    const float* __restrict__ vals, const float* __restrict__ mix,
    int* __restrict__ pos, int2* __restrict__ csr) {
    int e = blockIdx.x * 256 + threadIdx.x;
    if (e >= EDGES_TOTAL) return;
    int a = e / NNZ;
    int row = rows[e];
    int p = atomicAdd(&pos[row], 1);
    float v = vals[e] * mix[a + 1];
    csr[p] = make_int2(cols[e], __float_as_int(v));
}

// ---------------------------------------------------------------------------
// Pull: one half-wave (32 lanes x float4) per destination row. Registers
// accumulate; rep row written exactly once. No float atomics anywhere.
// ---------------------------------------------------------------------------
__global__ __launch_bounds__(256) void pull_kernel(
    const int* __restrict__ offsets, const int2* __restrict__ csr,
    const float4* __restrict__ in4, float4* __restrict__ rep4,
    const float* __restrict__ mix) {
    long long gid = (long long)blockIdx.x * 256 + threadIdx.x;
    int row = (int)(gid >> 5);
    int l = (int)(gid & 31);
    if (row >= N_NODES) return;
    int j = offsets[row];
    int end = offsets[row + 1];
    float m0 = mix[0];
    float4 x = in4[(long long)row * 32 + l];
    float4 acc = make_float4(m0 * x.x, m0 * x.y, m0 * x.z, m0 * x.w);
    // unrolled-by-2 to keep two gathers in flight
    for (; j + 1 < end; j += 2) {
        int2 e0 = csr[j];
        int2 e1 = csr[j + 1];
        float v0 = __int_as_float(e0.y);
        float v1 = __int_as_float(e1.y);
        float4 y0 = in4[(long long)e0.x * 32 + l];
        float4 y1 = in4[(long long)e1.x * 32 + l];
        acc.x += v0 * y0.x; acc.y += v0 * y0.y; acc.z += v0 * y0.z; acc.w += v0 * y0.w;
        acc.x += v1 * y1.x; acc.y += v1 * y1.y; acc.z += v1 * y1.z; acc.w += v1 * y1.w;
    }
    if (j < end) {
        int2 e0 = csr[j];
        float v0 = __int_as_float(e0.y);
        float4 y0 = in4[(long long)e0.x * 32 + l];
        acc.x += v0 * y0.x; acc.y += v0 * y0.y; acc.z += v0 * y0.z; acc.w += v0 * y0.w;
    }
    rep4[(long long)row * 32 + l] = acc;
}

// ---------------------------------------------------------------------------
// Fallback path (small ws): rep = mix[0]*input, then atomic push-scatter
// ---------------------------------------------------------------------------
__global__ __launch_bounds__(256) void rep_init_kernel(
    const float4* __restrict__ in4, float4* __restrict__ rep4,
    const float* __restrict__ mix) {
    int i = blockIdx.x * blockDim.x + threadIdx.x;
    if (i >= N_NODES * D / 4) return;
    float m0 = mix[0];
    float4 v = in4[i];
    v.x *= m0; v.y *= m0; v.z *= m0; v.w *= m0;
    rep4[i] = v;
}

__global__ __launch_bounds__(256) void scatter_kernel(
    const int* __restrict__ rows, const int* __restrict__ cols,
    const float* __restrict__ vals, const float4* __restrict__ in4,
    float* __restrict__ rep, const float* __restrict__ mix) {
    long long gid = (long long)blockIdx.x * blockDim.x + threadIdx.x;
    int e = (int)(gid >> 5);
    int l = (int)(gid & 31);
    if (e >= EDGES_TOTAL) return;
    int a = e / NNZ;
    int row = rows[e];
    int col = cols[e];
    float v = vals[e] * mix[a + 1];
    float4 x = in4[col * 32 + l];
    float* dst = rep + (long long)row * D + l * 4;
    atomicAdd(dst + 0, v * x.x);
    atomicAdd(dst + 1, v * x.y);
    atomicAdd(dst + 2, v * x.z);
    atomicAdd(dst + 3, v * x.w);
}

// ---------------------------------------------------------------------------
// out = rep @ W + bias. W (64KB f32) staged in LDS; 8 rows x 32 col-groups.
// ---------------------------------------------------------------------------
__global__ __launch_bounds__(256) void gemm_kernel(
    const float4* __restrict__ rep4, const float4* __restrict__ w4,
    const float4* __restrict__ bias4, float4* __restrict__ out4) {
    __shared__ float4 Wlds[D * (D / 4)];

    for (int idx = threadIdx.x; idx < D * (D / 4); idx += 256)
        Wlds[idx] = w4[idx];
    __syncthreads();

    int tc = threadIdx.x & 31;
    int rlocal = threadIdx.x >> 5;

    for (int base = blockIdx.x * 8; base < N_NODES; base += gridDim.x * 8) {
        int row = base + rlocal;
        if (row >= N_NODES) continue;
        float4 acc = make_float4(0.f, 0.f, 0.f, 0.f);
        const float4* reprow = rep4 + (long long)row * (D / 4);
        #pragma unroll 4
        for (int k4 = 0; k4 < D / 4; ++k4) {
            float4 a = reprow[k4];
            float4 w0 = Wlds[(k4 * 4 + 0) * 32 + tc];
            float4 w1 = Wlds[(k4 * 4 + 1) * 32 + tc];
            float4 w2 = Wlds[(k4 * 4 + 2) * 32 + tc];
            float4 w3 = Wlds[(k4 * 4 + 3) * 32 + tc];
            acc.x += a.x * w0.x; acc.y += a.x * w0.y; acc.z += a.x * w0.z; acc.w += a.x * w0.w;
            acc.x += a.y * w1.x; acc.y += a.y * w1.y; acc.z += a.y * w1.z; acc.w += a.y * w1.w;
            acc.x += a.z * w2.x; acc.y += a.z * w2.y; acc.z += a.z * w2.z; acc.w += a.z * w2.w;
            acc.x += a.w * w3.x; acc.y += a.w * w3.y; acc.z += a.w * w3.z; acc.w += a.w * w3.w;
        }
        float4 b = bias4[tc];
        acc.x += b.x; acc.y += b.y; acc.z += b.z; acc.w += b.w;
        out4[(long long)row * (D / 4) + tc] = acc;
    }
}

// ---------------------------------------------------------------------------
extern "C" void kernel_launch(void* const* d_in, const int* in_sizes, int n_in,
                              void* d_out, int out_size, void* d_ws, size_t ws_size,
                              hipStream_t stream) {
    const float* input         = (const float*)d_in[0];
    const int*   adj_rows      = (const int*)d_in[1];
    const int*   adj_cols      = (const int*)d_in[2];
    const float* adj_vals      = (const float*)d_in[3];
    const float* weight        = (const float*)d_in[4];
    const float* linear_weight = (const float*)d_in[5];
    const float* bias          = (const float*)d_in[6];

    float* out = (float*)d_out;                    // [N_NODES, D]
    float* rep = out + (size_t)N_NODES * D;        // [N_NODES, D]

    // workspace layout
    char* ws = (char*)d_ws;
    float* mix      = (float*)ws;                        ws += 32;
    int*   counts   = (int*)ws;                          ws += sizeof(int) * N_NODES;
    int*   offsets  = (int*)ws;                          ws += sizeof(int) * (N_NODES + 4);
    int*   pos      = (int*)ws;                          ws += sizeof(int) * N_NODES;
    int*   blockSums= (int*)ws;                          ws += sizeof(int) * 128;
    // align csr to 16B
    ws = (char*)(((uintptr_t)ws + 15) & ~(uintptr_t)15);
    int2*  csr      = (int2*)ws;                         ws += sizeof(int2) * EDGES_TOTAL;
    size_t needed = (size_t)(ws - (char*)d_ws);

    // Phase 0: softmax of mixing weights
    softmax_mix_kernel<<<1, 64, 0, stream>>>(linear_weight, mix);

    if (ws_size >= needed) {
        // ---- CSR pull path ----
        hipMemsetAsync(counts, 0, sizeof(int) * N_NODES, stream);

        {   // histogram
            int blocks = (EDGES_TOTAL + 255) / 256;
            hist_kernel<<<blocks, 256, 0, stream>>>(adj_rows, counts);
        }
        scan_partial_kernel<<<SCAN_BLOCKS, 256, 0, stream>>>(counts, blockSums);
        scan_blocksums_kernel<<<1, 64, 0, stream>>>(blockSums);
        scan_final_kernel<<<SCAN_BLOCKS, 256, 0, stream>>>(counts, blockSums, offsets, pos);
        {   // scatter into CSR
            int blocks = (EDGES_TOTAL + 255) / 256;
            build_csr_kernel<<<blocks, 256, 0, stream>>>(
                adj_rows, adj_cols, adj_vals, mix, pos, csr);
        }
        {   // pull: rep = mix0*input + sum_e val*input[col]
            long long threads = (long long)N_NODES * 32;
            int blocks = (int)((threads + 255) / 256);
            pull_kernel<<<blocks, 256, 0, stream>>>(
                offsets, csr, (const float4*)input, (float4*)rep, mix);
        }
    } else {
        // ---- fallback: atomic push-scatter ----
        {
            int total = N_NODES * D / 4;
            int blocks = (total + 255) / 256;
            rep_init_kernel<<<blocks, 256, 0, stream>>>(
                (const float4*)input, (float4*)rep, mix);
        }
        {
            long long threads = (long long)EDGES_TOTAL * 32;
            int blocks = (int)((threads + 255) / 256);
            scatter_kernel<<<blocks, 256, 0, stream>>>(
                adj_rows, adj_cols, adj_vals, (const float4*)input, rep, mix);
        }
    }

    // Phase 3: out = rep @ W + bias
    gemm_kernel<<<2048, 256, 0, stream>>>(
        (const float4*)rep, (const float4*)weight,
        (const float4*)bias, (float4*)out);
}

// Round 3
// 750.872 us; speedup vs baseline: 8.3186x; 1.2162x over previous
//
#include <hip/hip_runtime.h>

#define N_NODES 100000
#define D 128
#define N_ADJ 6
#define NNZ 600000
#define N_HOPS 7
#define EDGES_TOTAL (N_ADJ * NNZ)

#define SCAN_CHUNK 1024
#define SCAN_BLOCKS ((N_NODES + SCAN_CHUNK - 1) / SCAN_CHUNK)  // 98

#define B_SHIFT 7
#define B_ROWS 128
#define NB ((N_NODES + B_ROWS - 1) / B_ROWS)   // 782 buckets
#define CHUNK 4096                              // edges per passA workgroup
#define EPT 16                                  // edges per thread (CHUNK/256)

// ---------------------------------------------------------------------------
// Phase 0: mix = softmax(linear_weight), 7 elements
// ---------------------------------------------------------------------------
__global__ void softmax_mix_kernel(const float* __restrict__ lw,
                                   float* __restrict__ mix) {
    if (threadIdx.x == 0) {
        float m = lw[0];
        for (int i = 1; i < N_HOPS; ++i) m = fmaxf(m, lw[i]);
        float e[N_HOPS];
        float s = 0.f;
        for (int i = 0; i < N_HOPS; ++i) { e[i] = __expf(lw[i] - m); s += e[i]; }
        float inv = 1.f / s;
        for (int i = 0; i < N_HOPS; ++i) mix[i] = e[i] * inv;
    }
}

// ---------------------------------------------------------------------------
// Row histogram (int atomics over 100k counters, low contention)
// ---------------------------------------------------------------------------
__global__ __launch_bounds__(256) void hist_kernel(
    const int* __restrict__ rows, int* __restrict__ counts) {
    int e = blockIdx.x * 256 + threadIdx.x;
    if (e < EDGES_TOTAL) atomicAdd(&counts[rows[e]], 1);
}

// ---------------------------------------------------------------------------
// Exclusive scan over row counts (3 kernels) -> offsets
// ---------------------------------------------------------------------------
__global__ __launch_bounds__(256) void scan_partial_kernel(
    const int* __restrict__ counts, int* __restrict__ blockSums) {
    __shared__ int lds[256];
    int base = blockIdx.x * SCAN_CHUNK;
    int t = threadIdx.x;
    int s = 0;
    #pragma unroll
    for (int k = 0; k < 4; ++k) {
        int i = base + t * 4 + k;
        s += (i < N_NODES) ? counts[i] : 0;
    }
    lds[t] = s;
    __syncthreads();
    for (int off = 128; off > 0; off >>= 1) {
        if (t < off) lds[t] += lds[t + off];
        __syncthreads();
    }
    if (t == 0) blockSums[blockIdx.x] = lds[0];
}

__global__ void scan_blocksums_kernel(int* __restrict__ blockSums) {
    if (threadIdx.x == 0) {
        int run = 0;
        for (int i = 0; i < SCAN_BLOCKS; ++i) {
            int c = blockSums[i];
            blockSums[i] = run;
            run += c;
        }
    }
}

__global__ __launch_bounds__(256) void scan_final_kernel(
    const int* __restrict__ counts, const int* __restrict__ blockSums,
    int* __restrict__ offsets) {
    __shared__ int lds[256];
    int base = blockIdx.x * SCAN_CHUNK;
    int t = threadIdx.x;
    int c[4];
    int s = 0;
    #pragma unroll
    for (int k = 0; k < 4; ++k) {
        int i = base + t * 4 + k;
        c[k] = (i < N_NODES) ? counts[i] : 0;
        s += c[k];
    }
    lds[t] = s;
    __syncthreads();
    for (int off = 1; off < 256; off <<= 1) {
        int u = 0;
        if (t >= off) u = lds[t - off];
        __syncthreads();
        if (t >= off) lds[t] += u;
        __syncthreads();
    }
    int texcl = lds[t] - s;
    int run = blockSums[blockIdx.x] + texcl;
    #pragma unroll
    for (int k = 0; k < 4; ++k) {
        int i = base + t * 4 + k;
        if (i < N_NODES) offsets[i] = run;
        run += c[k];
    }
    if (blockIdx.x == 0 && t == 0) offsets[N_NODES] = EDGES_TOTAL;
}

// ---------------------------------------------------------------------------
// bpos[b] = offsets[b*128]  (bucket write cursors for pass A)
// ---------------------------------------------------------------------------
__global__ void bpos_init_kernel(const int* __restrict__ offsets,
                                 int* __restrict__ bpos) {
    int b = blockIdx.x * 256 + threadIdx.x;
    if (b < NB) bpos[b] = offsets[b << B_SHIFT];
}

// ---------------------------------------------------------------------------
// Pass A: LDS-aggregated bucket scatter. Each WG stages a 4096-edge chunk in
// LDS grouped by bucket (row>>7), then flushes contiguous per-bucket runs to
// the bucketed tmp array. Payload: {rowLocal(7b)<<25 | col, premixed val}.
// Turns 223MB of partial-line random writes into ~45MB of short runs.
// ---------------------------------------------------------------------------
__global__ __launch_bounds__(256) void bucket_scatter_kernel(
    const int* __restrict__ rows, const int* __restrict__ cols,
    const float* __restrict__ vals, const float* __restrict__ mix,
    int* __restrict__ bpos, int2* __restrict__ tmp) {
    __shared__ int cnt[NB];
    __shared__ int off[NB];
    __shared__ int gbase[NB];
    __shared__ int scanbuf[256];
    __shared__ int2 stage[CHUNK];

    int base = blockIdx.x * CHUNK;
    int t = threadIdx.x;

    for (int i = t; i < NB; i += 256) cnt[i] = 0;
    __syncthreads();

    // Phase 1: count + capture slots
    int myRow[EPT];
    int mySlot[EPT];
    #pragma unroll
    for (int k = 0; k < EPT; ++k) {
        int e = base + k * 256 + t;
        if (e < EDGES_TOTAL) {
            int r = rows[e];
            myRow[k] = r;
            mySlot[k] = atomicAdd(&cnt[r >> B_SHIFT], 1);
        } else {
            myRow[k] = -1;
            mySlot[k] = 0;
        }
    }
    __syncthreads();

    // Exclusive scan of cnt[0..NB) (each thread owns 4 buckets)
    int i0 = t * 4;
    int c4[4];
    int s = 0;
    #pragma unroll
    for (int k = 0; k < 4; ++k) {
        int i = i0 + k;
        c4[k] = (i < NB) ? cnt[i] : 0;
        s += c4[k];
    }
    scanbuf[t] = s;
    __syncthreads();
    for (int o = 1; o < 256; o <<= 1) {
        int u = 0;
        if (t >= o) u = scanbuf[t - o];
        __syncthreads();
        if (t >= o) scanbuf[t] += u;
        __syncthreads();
    }
    int run = scanbuf[t] - s;
    #pragma unroll
    for (int k = 0; k < 4; ++k) {
        int i = i0 + k;
        if (i < NB) off[i] = run;
        run += c4[k];
    }
    // Reserve global ranges (one atomic per bucket per chunk)
    for (int i = t; i < NB; i += 256)
        gbase[i] = atomicAdd(&bpos[i], cnt[i]);
    __syncthreads();

    // Phase 2: place edges into LDS stage, bucket-grouped
    #pragma unroll
    for (int k = 0; k < EPT; ++k) {
        int e = base + k * 256 + t;
        int r = myRow[k];
        if (r >= 0) {
            int b = r >> B_SHIFT;
            int rl = r & (B_ROWS - 1);
            int a = e / NNZ;
            float v = vals[e] * mix[a + 1];
            int packed = (rl << 25) | cols[e];
            stage[off[b] + mySlot[k]] = make_int2(packed, __float_as_int(v));
        }
    }
    __syncthreads();

    // Phase 3: flush contiguous per-bucket runs to global
    for (int i = t; i < NB; i += 256) {
        int c = cnt[i];
        int g = gbase[i];
        int o = off[i];
        for (int j = 0; j < c; ++j) tmp[g + j] = stage[o + j];
    }
}

// ---------------------------------------------------------------------------
// Pass B: one WG per bucket. Reorder the bucket's edges into exact CSR order.
// Destination window ~37KB, single-CU -> full-line writebacks. Row cursors
// in LDS (no global atomics).
// ---------------------------------------------------------------------------
__global__ __launch_bounds__(256) void bucket_to_csr_kernel(
    const int* __restrict__ offsets, const int2* __restrict__ tmp,
    int2* __restrict__ csr) {
    __shared__ int lpos[B_ROWS];
    int b = blockIdx.x;
    int rbase = b << B_SHIFT;
    int t = threadIdx.x;
    if (t < B_ROWS) {
        int r = rbase + t;
        lpos[t] = offsets[(r < N_NODES) ? r : N_NODES];
    }
    __syncthreads();
    int start = offsets[rbase];
    int endr = rbase + B_ROWS;
    int end = offsets[(endr < N_NODES) ? endr : N_NODES];
    for (int j = start + t; j < end; j += 256) {
        int2 eo = tmp[j];
        int rl = ((unsigned)eo.x) >> 25;
        int col = eo.x & 0x01FFFFFF;
        int p = atomicAdd(&lpos[rl], 1);
        csr[p] = make_int2(col, eo.y);
    }
}

// ---------------------------------------------------------------------------
// Pull: half-wave (32 lanes x float4) per destination row, register acc.
// ---------------------------------------------------------------------------
__global__ __launch_bounds__(256) void pull_kernel(
    const int* __restrict__ offsets, const int2* __restrict__ csr,
    const float4* __restrict__ in4, float4* __restrict__ rep4,
    const float* __restrict__ mix) {
    long long gid = (long long)blockIdx.x * 256 + threadIdx.x;
    int row = (int)(gid >> 5);
    int l = (int)(gid & 31);
    if (row >= N_NODES) return;
    int j = offsets[row];
    int end = offsets[row + 1];
    float m0 = mix[0];
    float4 x = in4[(long long)row * 32 + l];
    float4 acc = make_float4(m0 * x.x, m0 * x.y, m0 * x.z, m0 * x.w);
    for (; j + 1 < end; j += 2) {
        int2 e0 = csr[j];
        int2 e1 = csr[j + 1];
        float v0 = __int_as_float(e0.y);
        float v1 = __int_as_float(e1.y);
        float4 y0 = in4[(long long)e0.x * 32 + l];
        float4 y1 = in4[(long long)e1.x * 32 + l];
        acc.x += v0 * y0.x; acc.y += v0 * y0.y; acc.z += v0 * y0.z; acc.w += v0 * y0.w;
        acc.x += v1 * y1.x; acc.y += v1 * y1.y; acc.z += v1 * y1.z; acc.w += v1 * y1.w;
    }
    if (j < end) {
        int2 e0 = csr[j];
        float v0 = __int_as_float(e0.y);
        float4 y0 = in4[(long long)e0.x * 32 + l];
        acc.x += v0 * y0.x; acc.y += v0 * y0.y; acc.z += v0 * y0.z; acc.w += v0 * y0.w;
    }
    rep4[(long long)row * 32 + l] = acc;
}

// ---------------------------------------------------------------------------
// Fallback path (small ws): rep = mix[0]*input, then atomic push-scatter
// ---------------------------------------------------------------------------
__global__ __launch_bounds__(256) void rep_init_kernel(
    const float4* __restrict__ in4, float4* __restrict__ rep4,
    const float* __restrict__ mix) {
    int i = blockIdx.x * blockDim.x + threadIdx.x;
    if (i >= N_NODES * D / 4) return;
    float m0 = mix[0];
    float4 v = in4[i];
    v.x *= m0; v.y *= m0; v.z *= m0; v.w *= m0;
    rep4[i] = v;
}

__global__ __launch_bounds__(256) void scatter_kernel(
    const int* __restrict__ rows, const int* __restrict__ cols,
    const float* __restrict__ vals, const float4* __restrict__ in4,
    float* __restrict__ rep, const float* __restrict__ mix) {
    long long gid = (long long)blockIdx.x * blockDim.x + threadIdx.x;
    int e = (int)(gid >> 5);
    int l = (int)(gid & 31);
    if (e >= EDGES_TOTAL) return;
    int a = e / NNZ;
    int row = rows[e];
    int col = cols[e];
    float v = vals[e] * mix[a + 1];
    float4 x = in4[col * 32 + l];
    float* dst = rep + (long long)row * D + l * 4;
    atomicAdd(dst + 0, v * x.x);
    atomicAdd(dst + 1, v * x.y);
    atomicAdd(dst + 2, v * x.z);
    atomicAdd(dst + 3, v * x.w);
}

// ---------------------------------------------------------------------------
// out = rep @ W + bias. W (64KB f32) staged in LDS; 8 rows x 32 col-groups.
// ---------------------------------------------------------------------------
__global__ __launch_bounds__(256) void gemm_kernel(
    const float4* __restrict__ rep4, const float4* __restrict__ w4,
    const float4* __restrict__ bias4, float4* __restrict__ out4) {
    __shared__ float4 Wlds[D * (D / 4)];

    for (int idx = threadIdx.x; idx < D * (D / 4); idx += 256)
        Wlds[idx] = w4[idx];
    __syncthreads();

    int tc = threadIdx.x & 31;
    int rlocal = threadIdx.x >> 5;

    for (int base = blockIdx.x * 8; base < N_NODES; base += gridDim.x * 8) {
        int row = base + rlocal;
        if (row >= N_NODES) continue;
        float4 acc = make_float4(0.f, 0.f, 0.f, 0.f);
        const float4* reprow = rep4 + (long long)row * (D / 4);
        #pragma unroll 4
        for (int k4 = 0; k4 < D / 4; ++k4) {
            float4 a = reprow[k4];
            float4 w0 = Wlds[(k4 * 4 + 0) * 32 + tc];
            float4 w1 = Wlds[(k4 * 4 + 1) * 32 + tc];
            float4 w2 = Wlds[(k4 * 4 + 2) * 32 + tc];
            float4 w3 = Wlds[(k4 * 4 + 3) * 32 + tc];
            acc.x += a.x * w0.x; acc.y += a.x * w0.y; acc.z += a.x * w0.z; acc.w += a.x * w0.w;
            acc.x += a.y * w1.x; acc.y += a.y * w1.y; acc.z += a.y * w1.z; acc.w += a.y * w1.w;
            acc.x += a.z * w2.x; acc.y += a.z * w2.y; acc.z += a.z * w2.z; acc.w += a.z * w2.w;
            acc.x += a.w * w3.x; acc.y += a.w * w3.y; acc.z += a.w * w3.z; acc.w += a.w * w3.w;
        }
        float4 b = bias4[tc];
        acc.x += b.x; acc.y += b.y; acc.z += b.z; acc.w += b.w;
        out4[(long long)row * (D / 4) + tc] = acc;
    }
}

// ---------------------------------------------------------------------------
extern "C" void kernel_launch(void* const* d_in, const int* in_sizes, int n_in,
                              void* d_out, int out_size, void* d_ws, size_t ws_size,
                              hipStream_t stream) {
    const float* input         = (const float*)d_in[0];
    const int*   adj_rows      = (const int*)d_in[1];
    const int*   adj_cols      = (const int*)d_in[2];
    const float* adj_vals      = (const float*)d_in[3];
    const float* weight        = (const float*)d_in[4];
    const float* linear_weight = (const float*)d_in[5];
    const float* bias          = (const float*)d_in[6];

    float* out = (float*)d_out;                    // [N_NODES, D]
    float* rep = out + (size_t)N_NODES * D;        // [N_NODES, D]

    // tmp (bucketed edges) aliases the `out` region: out is only written by
    // the final gemm, after tmp's lifetime (passA write -> passB read) ends.
    int2* tmp = (int2*)out;                        // 28.8MB <= 51.2MB

    // workspace layout
    char* ws = (char*)d_ws;
    float* mix      = (float*)ws;                        ws += 32;
    int*   counts   = (int*)ws;                          ws += sizeof(int) * N_NODES;
    int*   offsets  = (int*)ws;                          ws += sizeof(int) * (N_NODES + 4);
    int*   blockSums= (int*)ws;                          ws += sizeof(int) * 128;
    int*   bpos     = (int*)ws;                          ws += sizeof(int) * (NB + 2);
    ws = (char*)(((uintptr_t)ws + 15) & ~(uintptr_t)15);
    int2*  csr      = (int2*)ws;                         ws += sizeof(int2) * EDGES_TOTAL;
    size_t needed = (size_t)(ws - (char*)d_ws);

    softmax_mix_kernel<<<1, 64, 0, stream>>>(linear_weight, mix);

    if (ws_size >= needed) {
        hipMemsetAsync(counts, 0, sizeof(int) * N_NODES, stream);
        {
            int blocks = (EDGES_TOTAL + 255) / 256;
            hist_kernel<<<blocks, 256, 0, stream>>>(adj_rows, counts);
        }
        scan_partial_kernel<<<SCAN_BLOCKS, 256, 0, stream>>>(counts, blockSums);
        scan_blocksums_kernel<<<1, 64, 0, stream>>>(blockSums);
        scan_final_kernel<<<SCAN_BLOCKS, 256, 0, stream>>>(counts, blockSums, offsets);
        bpos_init_kernel<<<(NB + 255) / 256, 256, 0, stream>>>(offsets, bpos);
        {
            int blocks = (EDGES_TOTAL + CHUNK - 1) / CHUNK;
            bucket_scatter_kernel<<<blocks, 256, 0, stream>>>(
                adj_rows, adj_cols, adj_vals, mix, bpos, tmp);
        }
        bucket_to_csr_kernel<<<NB, 256, 0, stream>>>(offsets, tmp, csr);
        {
            long long threads = (long long)N_NODES * 32;
            int blocks = (int)((threads + 255) / 256);
            pull_kernel<<<blocks, 256, 0, stream>>>(
                offsets, csr, (const float4*)input, (float4*)rep, mix);
        }
    } else {
        {
            int total = N_NODES * D / 4;
            int blocks = (total + 255) / 256;
            rep_init_kernel<<<blocks, 256, 0, stream>>>(
                (const float4*)input, (float4*)rep, mix);
        }
        {
            long long threads = (long long)EDGES_TOTAL * 32;
            int blocks = (int)((threads + 255) / 256);
            scatter_kernel<<<blocks, 256, 0, stream>>>(
                adj_rows, adj_cols, adj_vals, (const float4*)input, rep, mix);
        }
    }

    gemm_kernel<<<2048, 256, 0, stream>>>(
        (const float4*)rep, (const float4*)weight,
        (const float4*)bias, (float4*)out);
}